// Round 6
// baseline (29799.942 us; speedup 1.0000x reference)
//
#include <hip/hip_runtime.h>
#include <hip/hip_bf16.h>
#include <math.h>

#define BB 64
#define SS 64
#define DA 512
#define DM 2048
#define MM 25
#define NH 8
#define HD 64
#define NS 512
#define NOUT 1000
#define TT 50
#define HN 32
#define KTOT 2560
#define NOUT2 4096
#define NPAD 1024
#define NBLK 256
#define SB2 ((size_t)BB*NS)

typedef __attribute__((ext_vector_type(8))) short bf16x8_t;
typedef __attribute__((ext_vector_type(8))) unsigned short u16x8_t;
typedef __attribute__((ext_vector_type(4))) float f32x4_t;

__device__ inline float bfs2f(unsigned short u){
    unsigned int x = ((unsigned int)u) << 16;
    return __uint_as_float(x);
}
__device__ inline unsigned short f2bfu(float v){
    __hip_bfloat16 h = __float2bfloat16(v);
    return *reinterpret_cast<unsigned short*>(&h);
}
__device__ inline float gelu_tanh(float x){
    float x3 = x*x*x;
    float u = 0.7978845608028654f*(x + 0.044715f*x3);
    float eu = __expf(2.f*u);
    float th = 1.f - 2.f/(eu + 1.f);
    return 0.5f*x*(1.0f + th);
}

// ---------------- workspace layout (float units) ----------------
static const size_t OFF_K     = 0;                       // bf16 Kb [B*S][512]
static const size_t OFF_V     = OFF_K     + 1048576;     // bf16 Vb [B*S][512]
static const size_t OFF_VT    = OFF_V     + 1048576;     // bf16 Vt [b][h][d][s]
static const size_t OFF_WCT   = OFF_VT    + 1048576;     // bf16 WcT [4096][2560]
static const size_t OFF_WC1   = OFF_WCT   + 5242880;     // bf16 Wc1 [k][n] 512x512
static const size_t OFF_WOUTT = OFF_WC1   + 131072;      // bf16 WoutT [1024][512]
static const size_t OFF_NW1B  = OFF_WOUTT + 262144;      // bf16 nw1 [2048][25][32]
static const size_t OFF_WFK   = OFF_NW1B  + 819200;
static const size_t OFF_WFV   = OFF_WFK   + 262144;
static const size_t OFF_BFK   = OFF_WFV   + 262144;
static const size_t OFF_BFV   = OFF_BFK   + 512;
static const size_t OFF_BC1   = OFF_BFV   + 512;
static const size_t OFF_BC2   = OFF_BC1   + 512;
static const size_t OFF_BOUTP = OFF_BC2   + 4096;
static const size_t OFF_AA    = OFF_BOUTP + 1024;        // f32 2x[64][512]
static const size_t OFF_BA    = OFF_AA    + 65536;
static const size_t OFF_AO    = OFF_BA    + 65536;
static const size_t OFF_BO    = OFF_AO    + 65536;
static const size_t OFF_ATT   = OFF_BO    + 65536;       // bf16 [64][512]
static const size_t OFF_SYO   = OFF_ATT   + 16384;       // bf16 [64][512]
static const size_t OFF_ACTB  = OFF_SYO   + 16384;       // bf16 [b][d]
static const size_t OFF_ACTF  = OFF_ACTB  + 65536;       // f32 [d][b]
static const size_t OFF_HP    = OFF_ACTF  + 131072;      // f32 [3][64][4096]
static const size_t OFF_SBUF  = OFF_HP    + 786432;      // f32 [b][2048]
static const size_t OFF_STATS = OFF_SBUF  + 131072;      // f32 [64][2]
static const size_t OFF_TRB   = OFF_STATS + 128;         // bf16 [25][2048][64]
static const size_t OFF_PREDA = OFF_TRB   + 1638400;     // bf16 [50][64][1024]
static const size_t OFF_END   = OFF_PREDA + 1638400;

// ---------------- setup kernels ----------------
__global__ void sgemm64(const float* __restrict__ A, int lda,
                        const float* __restrict__ Bm, int ldb,
                        const float* __restrict__ bias,
                        float* __restrict__ C, int ldc, int Kdim)
{
    __shared__ float la[16][65];
    __shared__ float lb[16][64];
    int cg = blockIdx.x, rg = blockIdx.y, tid = threadIdx.x;
    int tx = tid & 15, ty = tid >> 4;
    const float* Ab = A + (size_t)rg*64*lda;
    const float* Bb = Bm + (size_t)cg*64;
    float acc[4][4] = {};
    for (int k0 = 0; k0 < Kdim; k0 += 16){
        for (int i = tid; i < 1024; i += 256){
            int r = i >> 4, kk = i & 15;
            la[kk][r] = Ab[(size_t)r*lda + k0 + kk];
        }
        for (int i = tid; i < 1024; i += 256){
            int kk = i >> 6, c = i & 63;
            lb[kk][c] = Bb[(size_t)(k0+kk)*ldb + c];
        }
        __syncthreads();
        #pragma unroll
        for (int kk = 0; kk < 16; ++kk){
            float av[4], bv[4];
            #pragma unroll
            for (int i = 0; i < 4; ++i) av[i] = la[kk][ty*4+i];
            #pragma unroll
            for (int j = 0; j < 4; ++j) bv[j] = lb[kk][tx*4+j];
            #pragma unroll
            for (int i = 0; i < 4; ++i)
                #pragma unroll
                for (int j = 0; j < 4; ++j) acc[i][j] += av[i]*bv[j];
        }
        __syncthreads();
    }
    for (int i = 0; i < 4; ++i){
        int row = rg*64 + ty*4 + i;
        for (int j = 0; j < 4; ++j){
            int col = cg*64 + tx*4 + j;
            float v = acc[i][j];
            if (bias) v += bias[col];
            C[(size_t)row*ldc + col] = v;
        }
    }
}

__global__ void sgemm64_bf16out(const float* __restrict__ A, int lda,
                                const float* __restrict__ Bm, int ldb,
                                const float* __restrict__ bias,
                                unsigned short* __restrict__ C, int ldc, int Kdim)
{
    __shared__ float la[16][65];
    __shared__ float lb[16][64];
    int cg = blockIdx.x, rg = blockIdx.y, tid = threadIdx.x;
    int tx = tid & 15, ty = tid >> 4;
    const float* Ab = A + (size_t)rg*64*lda;
    const float* Bb = Bm + (size_t)cg*64;
    float acc[4][4] = {};
    for (int k0 = 0; k0 < Kdim; k0 += 16){
        for (int i = tid; i < 1024; i += 256){
            int r = i >> 4, kk = i & 15;
            la[kk][r] = Ab[(size_t)r*lda + k0 + kk];
        }
        for (int i = tid; i < 1024; i += 256){
            int kk = i >> 6, c = i & 63;
            lb[kk][c] = Bb[(size_t)(k0+kk)*ldb + c];
        }
        __syncthreads();
        #pragma unroll
        for (int kk = 0; kk < 16; ++kk){
            float av[4], bv[4];
            #pragma unroll
            for (int i = 0; i < 4; ++i) av[i] = la[kk][ty*4+i];
            #pragma unroll
            for (int j = 0; j < 4; ++j) bv[j] = lb[kk][tx*4+j];
            #pragma unroll
            for (int i = 0; i < 4; ++i)
                #pragma unroll
                for (int j = 0; j < 4; ++j) acc[i][j] += av[i]*bv[j];
        }
        __syncthreads();
    }
    for (int i = 0; i < 4; ++i){
        int row = rg*64 + ty*4 + i;
        for (int j = 0; j < 4; ++j){
            int col = cg*64 + tx*4 + j;
            float v = acc[i][j];
            if (bias) v += bias[col];
            C[(size_t)row*ldc + col] = f2bfu(v);
        }
    }
}

// Ct[n][k] = bf16((A@B)[k][n]); A 512x512, B 512xN (ldb)
__global__ void gemm_t_bf16(const float* __restrict__ A, const float* __restrict__ Bm,
                            int ldb, unsigned short* __restrict__ Ct, int ldct)
{
    __shared__ float la[16][65];
    __shared__ float lb[16][64];
    int cg = blockIdx.x, rg = blockIdx.y, tid = threadIdx.x;
    int tx = tid & 15, ty = tid >> 4;
    const float* Ab = A + (size_t)rg*64*512;
    const float* Bb = Bm + (size_t)cg*64;
    float acc[4][4] = {};
    for (int k0 = 0; k0 < 512; k0 += 16){
        for (int i = tid; i < 1024; i += 256){
            int r = i >> 4, kk = i & 15;
            la[kk][r] = Ab[(size_t)r*512 + k0 + kk];
        }
        for (int i = tid; i < 1024; i += 256){
            int kk = i >> 6, c = i & 63;
            lb[kk][c] = Bb[(size_t)(k0+kk)*ldb + c];
        }
        __syncthreads();
        #pragma unroll
        for (int kk = 0; kk < 16; ++kk){
            float av[4], bv[4];
            #pragma unroll
            for (int i = 0; i < 4; ++i) av[i] = la[kk][ty*4+i];
            #pragma unroll
            for (int j = 0; j < 4; ++j) bv[j] = lb[kk][tx*4+j];
            #pragma unroll
            for (int i = 0; i < 4; ++i)
                #pragma unroll
                for (int j = 0; j < 4; ++j) acc[i][j] += av[i]*bv[j];
        }
        __syncthreads();
    }
    for (int i = 0; i < 4; ++i){
        int krow = rg*64 + ty*4 + i;
        for (int j = 0; j < 4; ++j){
            int ncol = cg*64 + tx*4 + j;
            Ct[(size_t)ncol*ldct + krow] = f2bfu(acc[i][j]);
        }
    }
}

__global__ void tcvt_ws1(const float* __restrict__ Ws1, unsigned short* __restrict__ WcT)
{
    __shared__ float tile[32][33];
    int bx = blockIdx.x, by = blockIdx.y;
    int tx = threadIdx.x & 31, ty = threadIdx.x >> 5;
    for (int i = 0; i < 4; ++i){
        int r = by*32 + ty + i*8;
        tile[ty + i*8][tx] = Ws1[(size_t)(512 + r)*NOUT2 + bx*32 + tx];
    }
    __syncthreads();
    for (int i = 0; i < 4; ++i){
        int n = bx*32 + ty + i*8;
        int r = by*32 + tx;
        WcT[(size_t)n*KTOT + 512 + r] = f2bfu(tile[tx][ty + i*8]);
    }
}

__global__ void tcvt_wout(const float* __restrict__ Wout, const float* __restrict__ bout,
                          unsigned short* __restrict__ WoutT, float* __restrict__ boutp)
{
    int n = blockIdx.x;
    int tid = threadIdx.x;
    for (int k = tid; k < NS; k += 256)
        WoutT[(size_t)n*NS + k] = (n < NOUT) ? f2bfu(Wout[(size_t)k*NOUT + n]) : (unsigned short)0;
    if (tid == 0) boutp[n] = (n < NOUT) ? bout[n] : 0.f;
}

__global__ void bias_combo(const float* __restrict__ bvec, const float* __restrict__ W,
                           int ldw, const float* __restrict__ badd,
                           float* __restrict__ out, int N)
{
    int n = blockIdx.x*256 + threadIdx.x;
    if (n >= N) return;
    float acc = badd[n];
    for (int k = 0; k < 512; ++k) acc += bvec[k]*W[(size_t)k*ldw + n];
    out[n] = acc;
}

__global__ void cvt_bf16(const float* __restrict__ in, unsigned short* __restrict__ out, int n)
{
    int i = blockIdx.x*256 + threadIdx.x;
    if (i < n) out[i] = f2bfu(in[i]);
}

// Vt[b][h][d][s] = Vb[(b*64+s)*512 + h*64+d]
__global__ void vt_k(const unsigned short* __restrict__ Vb, unsigned short* __restrict__ Vt)
{
    int b = blockIdx.x;
    for (int i = threadIdx.x; i < SS*DA; i += 256){
        int s = i >> 9, c = i & 511;
        int h = c >> 6, d = c & 63;
        Vt[(((size_t)(b*NH + h)*HD + d)*SS) + s] = Vb[(size_t)(b*SS + s)*DA + c];
    }
}

__global__ void init_state(const float* __restrict__ ss,
                           const int* __restrict__ ilo, const int* __restrict__ iro,
                           float* __restrict__ act_f, unsigned short* __restrict__ act_bf,
                           float* __restrict__ aA0, float* __restrict__ bA0,
                           float* __restrict__ aO0, float* __restrict__ bO0)
{
    int i = blockIdx.x*256 + threadIdx.x;
    if (i < BB*DM){
        int d = i >> 6, b = i & 63;
        float v = ss[d];
        act_f[(size_t)d*BB + b] = v;
        act_bf[(size_t)b*DM + d] = f2bfu(v);
    }
    if (i < BB*NS){
        int j = i & (NS-1);
        aA0[i] = 0.f; bA0[i] = 0.f;
        aO0[i] = ss[ilo[j]]*ss[iro[j]];
        bO0[i] = 1.f;
    }
}

// ---------------- persistent kernel ----------------
struct CTMParams {
    const unsigned short *Kb, *Vt, *WcT, *Wc1, *WoutT, *nw1b;
    unsigned short *att, *syO, *act_bf, *traceb, *predA;
    float *act_f, *hp, *sbuf, *stats;
    const float *bc1, *bc2, *boutp, *lng, *lnb;
    const float *stt, *nb1, *nw2, *nb2;
    float *aA, *bA, *aO, *bO;
    const int *ila, *ira, *ilo, *iro;
    const float *dca, *dco;
    float *out_syo;
};

__device__ unsigned g_cnt = 0;
__device__ unsigned g_gen = 0;

__device__ inline void gbar(){
    __syncthreads();
    __threadfence();
    if (threadIdx.x == 0){
        unsigned g = __hip_atomic_load(&g_gen, __ATOMIC_RELAXED, __HIP_MEMORY_SCOPE_AGENT);
        unsigned a = __hip_atomic_fetch_add(&g_cnt, 1u, __ATOMIC_ACQ_REL, __HIP_MEMORY_SCOPE_AGENT);
        if (a == NBLK-1u){
            __hip_atomic_store(&g_cnt, 0u, __ATOMIC_RELAXED, __HIP_MEMORY_SCOPE_AGENT);
            __hip_atomic_fetch_add(&g_gen, 1u, __ATOMIC_RELEASE, __HIP_MEMORY_SCOPE_AGENT);
        } else {
            while (__hip_atomic_load(&g_gen, __ATOMIC_ACQUIRE, __HIP_MEMORY_SCOPE_AGENT) == g)
                __builtin_amdgcn_s_sleep(1);
        }
    }
    __syncthreads();
    __threadfence();
}

// syA(k) + Qh + attention for batch b.  512 threads.
__device__ inline void attn_chain(const CTMParams& P, char* smem, int b, int k)
{
    float* syA = (float*)smem;            // 512
    float* q   = syA + 512;               // 512
    float* wgt = q + 512;                 // 512  [h][s]
    float* qp  = wgt + 512;               // 8*512
    const int tid = threadIdx.x, lane = tid & 63, w = tid >> 6;
    const int rdn = k & 1;
    {   // syA
        int j = tid;
        float pl = P.act_f[(size_t)P.ila[j]*BB + b];
        float pr = P.act_f[(size_t)P.ira[j]*BB + b];
        float rr = __expf(-fminf(fmaxf(P.dca[j], 0.f), 15.f));
        size_t o = (size_t)b*NS + j;
        float a  = rr*P.aA[(size_t)rdn*SB2 + o] + pl*pr;
        float be = rr*P.bA[(size_t)rdn*SB2 + o] + 1.f;
        P.aA[(size_t)(1-rdn)*SB2 + o] = a;
        P.bA[(size_t)(1-rdn)*SB2 + o] = be;
        syA[j] = a*rsqrtf(be);
    }
    __syncthreads();
    {   // Qh partials: wave w covers k-range [w*64,(w+1)*64), lane covers 8 n-cols
        float acc[8] = {0,0,0,0,0,0,0,0};
        int nb = lane*8;
        const unsigned short* wp = P.Wc1 + (size_t)(w*64)*DA + nb;
        #pragma unroll 8
        for (int kk = 0; kk < 64; ++kk){
            float sv = syA[w*64 + kk];
            u16x8_t wv = *(const u16x8_t*)(wp + (size_t)kk*DA);
            #pragma unroll
            for (int u = 0; u < 8; ++u) acc[u] += sv*bfs2f(wv[u]);
        }
        #pragma unroll
        for (int u = 0; u < 8; ++u) qp[w*512 + nb + u] = acc[u];
    }
    __syncthreads();
    {   // reduce 8 wave-partials
        int n = tid;
        float acc = P.bc1[n];
        #pragma unroll
        for (int ww = 0; ww < 8; ++ww) acc += qp[ww*512 + n];
        q[n] = acc;
    }
    __syncthreads();
    {   // scores + softmax: wave h=w, lane=s
        int h = w, s = lane;
        const unsigned short* kp = P.Kb + (size_t)(b*SS + s)*DA + h*HD;
        float sc = 0.f;
        #pragma unroll
        for (int dg = 0; dg < 8; ++dg){
            u16x8_t kv = *(const u16x8_t*)(kp + dg*8);
            #pragma unroll
            for (int u = 0; u < 8; ++u) sc += q[h*64 + dg*8 + u]*bfs2f(kv[u]);
        }
        sc *= 0.125f;
        float m = sc;
        for (int o = 32; o; o >>= 1) m = fmaxf(m, __shfl_xor(m, o, 64));
        float e = __expf(sc - m);
        float sum = e;
        for (int o = 32; o; o >>= 1) sum += __shfl_xor(sum, o, 64);
        wgt[h*64 + s] = e/sum;
    }
    __syncthreads();
    {   // PV: wave h=w, lane=d, vectorized over s
        int h = w, d = lane;
        const unsigned short* vp = P.Vt + ((size_t)(b*NH + h)*HD + d)*SS;
        float o = 0.f;
        #pragma unroll
        for (int s8 = 0; s8 < 8; ++s8){
            u16x8_t vv = *(const u16x8_t*)(vp + s8*8);
            #pragma unroll
            for (int u = 0; u < 8; ++u) o += wgt[h*64 + s8*8 + u]*bfs2f(vv[u]);
        }
        P.att[(size_t)b*DA + h*HD + d] = f2bfu(o);
    }
}

// hgemm: full-K MFMA, idx in [0,192): XCD-swizzled (xcd=idx&7 owns 8 n-tiles)
__device__ inline void hgemm_phase(const CTMParams& P, char* smem, int idx)
{
    unsigned short* Al = (unsigned short*)smem;        // [64][72]
    unsigned short* Bl = Al + 64*72;
    const int tid = threadIdx.x, lane = tid & 63, w = tid >> 6;
    const int rf = w & 3, cf2 = (w >> 2)*2;
    const int colb = lane & 15, koff = (lane >> 4)*8, rg4 = (lane >> 4)*4;
    const int xcd = idx & 7, j = idx >> 3;
    const int nt = xcd*8 + (j & 7);
    const int kc = j >> 3;                             // 0..2
    const int kst0[3] = {0, 14, 27};
    const int kst1[3] = {14, 27, 40};
    const int n0 = nt*64;
    const int srow = tid >> 3, skg = (tid & 7)*8;
    f32x4_t acc0 = {0.f,0.f,0.f,0.f}, acc1 = {0.f,0.f,0.f,0.f};
    for (int st = kst0[kc]; st < kst1[kc]; ++st){
        int k0 = st*64;
        *(uint4*)&Bl[srow*72 + skg] =
            *(const uint4*)&P.WcT[(size_t)(n0 + srow)*KTOT + k0 + skg];
        uint4 av;
        if (k0 < 512) av = *(const uint4*)&P.att[(size_t)srow*DA + k0 + skg];
        else          av = *(const uint4*)&P.act_bf[(size_t)srow*DM + (k0 - 512) + skg];
        *(uint4*)&Al[srow*72 + skg] = av;
        __syncthreads();
        int arow = rf*16 + colb;
        bf16x8_t a0 = *(const bf16x8_t*)&Al[arow*72 + koff];
        bf16x8_t a1 = *(const bf16x8_t*)&Al[arow*72 + 32 + koff];
        int br0 = cf2*16 + colb, br1 = br0 + 16;
        bf16x8_t b00 = *(const bf16x8_t*)&Bl[br0*72 + koff];
        bf16x8_t b01 = *(const bf16x8_t*)&Bl[br0*72 + 32 + koff];
        bf16x8_t b10 = *(const bf16x8_t*)&Bl[br1*72 + koff];
        bf16x8_t b11 = *(const bf16x8_t*)&Bl[br1*72 + 32 + koff];
        acc0 = __builtin_amdgcn_mfma_f32_16x16x32_bf16(a0, b00, acc0, 0, 0, 0);
        acc0 = __builtin_amdgcn_mfma_f32_16x16x32_bf16(a1, b01, acc0, 0, 0, 0);
        acc1 = __builtin_amdgcn_mfma_f32_16x16x32_bf16(a0, b10, acc1, 0, 0, 0);
        acc1 = __builtin_amdgcn_mfma_f32_16x16x32_bf16(a1, b11, acc1, 0, 0, 0);
        __syncthreads();
    }
    float* out = P.hp + (size_t)kc*BB*NOUT2;
    #pragma unroll
    for (int r = 0; r < 4; ++r){
        int row = rf*16 + rg4 + r;
        out[(size_t)row*NOUT2 + n0 + cf2*16 + colb]       = acc0[r];
        out[(size_t)row*NOUT2 + n0 + (cf2 + 1)*16 + colb] = acc1[r];
    }
}

// pred: [64 b][1024 n] = syO @ WoutT^T, pb in [0,16)
__device__ inline void pred_phase(const CTMParams& P, char* smem, int pb, int tp)
{
    unsigned short* Al = (unsigned short*)smem;
    unsigned short* Bl = Al + 64*72;
    const int tid = threadIdx.x, lane = tid & 63, w = tid >> 6;
    const int rf = w & 3, cf2 = (w >> 2)*2;
    const int colb = lane & 15, koff = (lane >> 4)*8, rg4 = (lane >> 4)*4;
    const int n0 = pb*64;
    const int srow = tid >> 3, skg = (tid & 7)*8;
    f32x4_t acc0 = {0.f,0.f,0.f,0.f}, acc1 = {0.f,0.f,0.f,0.f};
    for (int st = 0; st < 8; ++st){
        int k0 = st*64;
        *(uint4*)&Bl[srow*72 + skg] =
            *(const uint4*)&P.WoutT[(size_t)(n0 + srow)*NS + k0 + skg];
        *(uint4*)&Al[srow*72 + skg] =
            *(const uint4*)&P.syO[(size_t)srow*NS + k0 + skg];
        __syncthreads();
        int arow = rf*16 + colb;
        bf16x8_t a0 = *(const bf16x8_t*)&Al[arow*72 + koff];
        bf16x8_t a1 = *(const bf16x8_t*)&Al[arow*72 + 32 + koff];
        int br0 = cf2*16 + colb, br1 = br0 + 16;
        bf16x8_t b00 = *(const bf16x8_t*)&Bl[br0*72 + koff];
        bf16x8_t b01 = *(const bf16x8_t*)&Bl[br0*72 + 32 + koff];
        bf16x8_t b10 = *(const bf16x8_t*)&Bl[br1*72 + koff];
        bf16x8_t b11 = *(const bf16x8_t*)&Bl[br1*72 + 32 + koff];
        acc0 = __builtin_amdgcn_mfma_f32_16x16x32_bf16(a0, b00, acc0, 0, 0, 0);
        acc0 = __builtin_amdgcn_mfma_f32_16x16x32_bf16(a1, b01, acc0, 0, 0, 0);
        acc1 = __builtin_amdgcn_mfma_f32_16x16x32_bf16(a0, b10, acc1, 0, 0, 0);
        acc1 = __builtin_amdgcn_mfma_f32_16x16x32_bf16(a1, b11, acc1, 0, 0, 0);
        __syncthreads();
    }
    unsigned short* pa = P.predA + (size_t)tp*BB*NPAD;
    #pragma unroll
    for (int r = 0; r < 4; ++r){
        int row = rf*16 + rg4 + r;
        int c0 = n0 + cf2*16 + colb, c1 = c0 + 16;
        pa[(size_t)row*NPAD + c0] = f2bfu(acc0[r] + P.boutp[c0]);
        pa[(size_t)row*NPAD + c1] = f2bfu(acc1[r] + P.boutp[c1]);
    }
}

// GLU + LN stats for batch b; writes sbuf[b][d] + stats[b]
__device__ inline void glu_phase(const CTMParams& P, char* smem, int b)
{
    float* red = (float*)smem;
    const int tid = threadIdx.x, lane = tid & 63, w = tid >> 6;
    float lsum = 0.f, lsq = 0.f;
    #pragma unroll
    for (int i = 0; i < 4; ++i){
        int d = tid + i*512;
        float h1 = P.bc2[d], h2 = P.bc2[DM + d];
        #pragma unroll
        for (int kc = 0; kc < 3; ++kc){
            const float* hb = P.hp + ((size_t)kc*BB + b)*NOUT2;
            h1 += hb[d]; h2 += hb[DM + d];
        }
        float s = h1*(1.f/(1.f + __expf(-h2)));
        P.sbuf[(size_t)b*DM + d] = s;
        lsum += s; lsq += s*s;
    }
    for (int o = 32; o; o >>= 1){ lsum += __shfl_down(lsum, o, 64); lsq += __shfl_down(lsq, o, 64); }
    if (lane == 0){ red[w] = lsum; red[8 + w] = lsq; }
    __syncthreads();
    if (tid == 0){
        float ts = 0.f, tq = 0.f;
        #pragma unroll
        for (int k2 = 0; k2 < 8; ++k2){ ts += red[k2]; tq += red[8 + k2]; }
        float mu = ts/DM;
        float var = tq/DM - mu*mu;
        P.stats[b*2] = mu;
        P.stats[b*2 + 1] = rsqrtf(var + 1e-5f);
    }
}

// nlm: wave w handles d = bid*8+w; lane = batch
__device__ inline void nlm_phase(const CTMParams& P, char* smem, int bid, int t)
{
    const int tid = threadIdx.x, lane = tid & 63, w = tid >> 6;
    const int d = bid*8 + w;
    float* wreg = (float*)smem + (size_t)w*864;   // [800 w1][32 nb1][32 nw2]
    for (int i = lane; i < 800; i += 64) wreg[i] = bfs2f(P.nw1b[(size_t)d*800 + i]);
    if (lane < 32) wreg[800 + lane] = P.nb1[d*HN + lane];
    else           wreg[832 + (lane - 32)] = P.nw2[d*HN + (lane - 32)];
    float mu  = P.stats[lane*2];
    float inv = P.stats[lane*2 + 1];
    float s   = P.sbuf[(size_t)lane*DM + d];
    float st  = (s - mu)*inv*P.lng[d] + P.lnb[d];
    int slot = t % MM;
    P.traceb[((size_t)slot*DM + d)*BB + lane] = f2bfu(st);
    float tr[25];
    #pragma unroll
    for (int m = 0; m < 24; ++m){
        int time = t - 24 + m;
        tr[m] = (time >= 0) ? bfs2f(P.traceb[((size_t)(time % MM)*DM + d)*BB + lane])
                            : P.stt[(size_t)d*MM + (m + t + 1)];
    }
    tr[24] = st;
    float a[32];
    #pragma unroll
    for (int h = 0; h < 32; ++h) a[h] = wreg[800 + h];
    #pragma unroll
    for (int m = 0; m < 25; ++m){
        float tm = tr[m];
        #pragma unroll
        for (int q4 = 0; q4 < 8; ++q4){
            float4 w4 = *(const float4*)&wreg[m*32 + q4*4];
            a[q4*4+0] += tm*w4.x;
            a[q4*4+1] += tm*w4.y;
            a[q4*4+2] += tm*w4.z;
            a[q4*4+3] += tm*w4.w;
        }
    }
    float pa = 0.f;
    #pragma unroll
    for (int h = 0; h < 32; ++h) pa += gelu_tanh(a[h])*wreg[832 + h];
    float v = pa + P.nb2[d];
    P.act_f[(size_t)d*BB + lane] = v;
    P.act_bf[(size_t)lane*DM + d] = f2bfu(v);
}

__device__ inline void syncO_phase(const CTMParams& P, int b, int t)
{
    int j = threadIdx.x;
    int rdn = t & 1;
    float pl = P.act_f[(size_t)P.ilo[j]*BB + b];
    float pr = P.act_f[(size_t)P.iro[j]*BB + b];
    float rr = __expf(-fminf(fmaxf(P.dco[j], 0.f), 15.f));
    size_t o = (size_t)b*NS + j;
    float a  = rr*P.aO[(size_t)rdn*SB2 + o] + pl*pr;
    float be = rr*P.bO[(size_t)rdn*SB2 + o] + 1.f;
    P.aO[(size_t)(1-rdn)*SB2 + o] = a;
    P.bO[(size_t)(1-rdn)*SB2 + o] = be;
    float s = a*rsqrtf(be);
    P.syO[o] = f2bfu(s);
    if (t == TT-1) P.out_syo[o] = s;
}

__global__ __launch_bounds__(512, 1) void ctm_loop(CTMParams P)
{
    __shared__ __align__(16) char smem[28672];
    const int bid = blockIdx.x;

    // prologue: syA(0)+Qh+att(0)
    if (bid < 64) attn_chain(P, smem, bid, 0);
    gbar();

    for (int t = 0; t < TT; ++t){
        // A: hgemm full-K (192) || pred(t-1) (16)
        if (bid < 192) hgemm_phase(P, smem, bid);
        else if (bid < 208){ if (t > 0) pred_phase(P, smem, bid - 192, t - 1); }
        gbar();
        // B: GLU + LN stats (64)
        if (bid < 64) glu_phase(P, smem, bid);
        gbar();
        // C: nlm (256 x 8 waves)
        nlm_phase(P, smem, bid, t);
        gbar();
        // D: attn chain for t+1 (64) || syncO(t) (64)
        if (bid < 64){ if (t < TT-1) attn_chain(P, smem, bid, t + 1); }
        else if (bid < 128) syncO_phase(P, bid - 64, t);
        gbar();
    }
    // final pred for t = TT-1
    if (bid < 16) pred_phase(P, smem, bid, TT - 1);
}

// ---------------- post-loop kernels ----------------
__global__ void entropy_k(const unsigned short* __restrict__ predA, float* __restrict__ out_cert)
{
    __shared__ float red[8];
    int b = blockIdx.x & 63, t = blockIdx.x >> 6, tid = threadIdx.x;
    const unsigned short* pr = predA + (size_t)t*BB*NPAD + (size_t)b*NPAD;
    float v[4];
    float m = -1e30f;
    #pragma unroll
    for (int i = 0; i < 4; ++i){
        int n = tid + i*256;
        v[i] = (n < NOUT) ? bfs2f(pr[n]) : -1e30f;
        m = fmaxf(m, v[i]);
    }
    for (int o = 32; o; o >>= 1) m = fmaxf(m, __shfl_xor(m, o, 64));
    if ((tid & 63) == 0) red[tid >> 6] = m;
    __syncthreads();
    m = fmaxf(fmaxf(red[0], red[1]), fmaxf(red[2], red[3]));
    __syncthreads();
    float s1 = 0.f, s2 = 0.f;
    #pragma unroll
    for (int i = 0; i < 4; ++i){
        int n = tid + i*256;
        if (n < NOUT){
            float e = __expf(v[i] - m);
            s1 += e; s2 += e*(v[i] - m);
        }
    }
    for (int o = 32; o; o >>= 1){ s1 += __shfl_xor(s1, o, 64); s2 += __shfl_xor(s2, o, 64); }
    if ((tid & 63) == 0){ red[tid >> 6] = s1; red[4 + (tid >> 6)] = s2; }
    __syncthreads();
    s1 = red[0]+red[1]+red[2]+red[3];
    s2 = red[4]+red[5]+red[6]+red[7];
    float plogp = s2/s1 - logf(s1);
    float ne = -plogp / logf((float)NOUT);
    if (tid == 0){
        out_cert[(size_t)b*2*TT + t]      = ne;
        out_cert[(size_t)b*2*TT + TT + t] = 1.f - ne;
    }
}

__global__ void transpose_pred(const unsigned short* __restrict__ predA, float* __restrict__ out_pred)
{
    __shared__ unsigned short sm[50][136];
    int bx = blockIdx.x;
    int b  = blockIdx.y;
    int tid = threadIdx.x;
    for (int tp = 0; tp < 25; ++tp){
        int t = tp*2 + (tid >> 7);
        int nn = tid & 127;
        sm[t][nn] = predA[(size_t)t*BB*NPAD + (size_t)b*NPAD + bx*128 + nn];
    }
    __syncthreads();
    int nloc = tid >> 1, half = tid & 1;
    int n = bx*128 + nloc;
    if (n < NOUT){
        float* dst = out_pred + (size_t)b*NOUT*TT + (size_t)n*TT + half*25;
        #pragma unroll
        for (int q = 0; q < 25; ++q) dst[q] = bfs2f(sm[half*25 + q][nloc]);
    }
}

extern "C" void kernel_launch(void* const* d_in, const int* in_sizes, int n_in,
                              void* d_out, int out_size, void* d_ws, size_t ws_size,
                              hipStream_t stream)
{
    const float* x    = (const float*)d_in[0];
    const float* Wf   = (const float*)d_in[1];
    const float* bf   = (const float*)d_in[2];
    const float* stt  = (const float*)d_in[3];
    const float* ss   = (const float*)d_in[4];
    const float* dca  = (const float*)d_in[5];
    const float* dco  = (const float*)d_in[6];
    const float* Wqp  = (const float*)d_in[7];
    const float* bqp  = (const float*)d_in[8];
    const float* Wq   = (const float*)d_in[9];
    const float* bq   = (const float*)d_in[10];
    const float* Wk   = (const float*)d_in[11];
    const float* bk   = (const float*)d_in[12];
    const float* Wv   = (const float*)d_in[13];
    const float* bv   = (const float*)d_in[14];
    const float* Wo   = (const float*)d_in[15];
    const float* bo   = (const float*)d_in[16];
    const float* Ws1  = (const float*)d_in[17];
    const float* bs1  = (const float*)d_in[18];
    const float* lng  = (const float*)d_in[19];
    const float* lnb  = (const float*)d_in[20];
    const float* nw1  = (const float*)d_in[21];
    const float* nb1  = (const float*)d_in[22];
    const float* nw2  = (const float*)d_in[23];
    const float* nb2  = (const float*)d_in[24];
    const float* Wout = (const float*)d_in[25];
    const float* bout = (const float*)d_in[26];
    const int* ila = (const int*)d_in[27];
    const int* ira = (const int*)d_in[28];
    const int* ilo = (const int*)d_in[29];
    const int* iro = (const int*)d_in[30];

    float* ws = (float*)d_ws;
    unsigned short* Kb    = (unsigned short*)(ws + OFF_K);
    unsigned short* Vb    = (unsigned short*)(ws + OFF_V);
    unsigned short* Vt    = (unsigned short*)(ws + OFF_VT);
    unsigned short* WcT   = (unsigned short*)(ws + OFF_WCT);
    unsigned short* Wc1b  = (unsigned short*)(ws + OFF_WC1);
    unsigned short* WoutT = (unsigned short*)(ws + OFF_WOUTT);
    unsigned short* nw1b  = (unsigned short*)(ws + OFF_NW1B);
    float* Wfk   = ws + OFF_WFK;
    float* Wfv   = ws + OFF_WFV;
    float* bfk   = ws + OFF_BFK;
    float* bfv   = ws + OFF_BFV;
    float* bc1   = ws + OFF_BC1;
    float* bc2   = ws + OFF_BC2;
    float* boutp = ws + OFF_BOUTP;
    float* aA    = ws + OFF_AA;
    float* bA    = ws + OFF_BA;
    float* aO    = ws + OFF_AO;
    float* bO    = ws + OFF_BO;
    unsigned short* attb  = (unsigned short*)(ws + OFF_ATT);
    unsigned short* syO   = (unsigned short*)(ws + OFF_SYO);
    unsigned short* actb  = (unsigned short*)(ws + OFF_ACTB);
    float* actf  = ws + OFF_ACTF;
    float* hp    = ws + OFF_HP;
    float* sbuf  = ws + OFF_SBUF;
    float* stats = ws + OFF_STATS;
    unsigned short* traceb = (unsigned short*)(ws + OFF_TRB);
    unsigned short* predA  = (unsigned short*)(ws + OFF_PREDA);

    float* outp = (float*)d_out;
    float* out_pred = outp;
    float* out_cert = outp + (size_t)BB*NOUT*TT;
    float* out_syo  = out_cert + (size_t)BB*2*TT;

    // ---- setup ----
    sgemm64<<<dim3(8,8),  256, 0, stream>>>(Wf, 512, Wk, 512, nullptr, Wfk, 512, 512);
    sgemm64<<<dim3(8,8),  256, 0, stream>>>(Wf, 512, Wv, 512, nullptr, Wfv, 512, 512);
    sgemm64_bf16out<<<dim3(8,8), 256, 0, stream>>>(Wqp, 512, Wq, 512, nullptr, Wc1b, 512, 512);
    gemm_t_bf16<<<dim3(64,8), 256, 0, stream>>>(Wo, Ws1, NOUT2, WcT, KTOT);
    tcvt_ws1<<<dim3(128,64), 256, 0, stream>>>(Ws1, WcT);
    tcvt_wout<<<NPAD, 256, 0, stream>>>(Wout, bout, WoutT, boutp);
    bias_combo<<<2, 256, 0, stream>>>(bf,  Wk, 512, bk, bfk, 512);
    bias_combo<<<2, 256, 0, stream>>>(bf,  Wv, 512, bv, bfv, 512);
    bias_combo<<<2, 256, 0, stream>>>(bqp, Wq, 512, bq, bc1, 512);
    bias_combo<<<16,256, 0, stream>>>(bo,  Ws1, NOUT2, bs1, bc2, 4096);
    cvt_bf16<<<6400, 256, 0, stream>>>(nw1, nw1b, DM*MM*HN);
    sgemm64_bf16out<<<dim3(8,64), 256, 0, stream>>>(x, 512, Wfk, 512, bfk, Kb, 512, 512);
    sgemm64_bf16out<<<dim3(8,64), 256, 0, stream>>>(x, 512, Wfv, 512, bfv, Vb, 512, 512);
    vt_k<<<BB, 256, 0, stream>>>(Vb, Vt);
    init_state<<<512, 256, 0, stream>>>(ss, ilo, iro, actf, actb, aA, bA, aO, bO);

    // ---- persistent loop ----
    CTMParams prm;
    prm.Kb = Kb; prm.Vt = Vt; prm.WcT = WcT; prm.Wc1 = Wc1b; prm.WoutT = WoutT; prm.nw1b = nw1b;
    prm.att = attb; prm.syO = syO; prm.act_bf = actb; prm.traceb = traceb; prm.predA = predA;
    prm.act_f = actf; prm.hp = hp; prm.sbuf = sbuf; prm.stats = stats;
    prm.bc1 = bc1; prm.bc2 = bc2; prm.boutp = boutp; prm.lng = lng; prm.lnb = lnb;
    prm.stt = stt; prm.nb1 = nb1; prm.nw2 = nw2; prm.nb2 = nb2;
    prm.aA = aA; prm.bA = bA; prm.aO = aO; prm.bO = bO;
    prm.ila = ila; prm.ira = ira; prm.ilo = ilo; prm.iro = iro;
    prm.dca = dca; prm.dco = dco;
    prm.out_syo = out_syo;
    void* args[] = { &prm };
    hipLaunchCooperativeKernel((const void*)ctm_loop, dim3(NBLK), dim3(512), args, 0, stream);

    // ---- outputs ----
    entropy_k<<<TT*BB, 256, 0, stream>>>(predA, out_cert);
    transpose_pred<<<dim3(8, BB), 256, 0, stream>>>(predA, out_pred);
}

// Round 8
// 4663.490 us; speedup vs baseline: 6.3901x; 6.3901x over previous
//
#include <hip/hip_runtime.h>
#include <hip/hip_bf16.h>
#include <math.h>

#define BB 64
#define SS 64
#define DA 512
#define DM 2048
#define MM 25
#define NH 8
#define HD 64
#define NS 512
#define NOUT 1000
#define TT 50
#define HN 32
#define KTOT 2560
#define NOUT2 4096
#define KCH 640
#define NPAD 1024
#define SB2 ((size_t)BB*NS)

typedef __attribute__((ext_vector_type(8))) short bf16x8_t;
typedef __attribute__((ext_vector_type(8))) unsigned short u16x8_t;
typedef __attribute__((ext_vector_type(4))) float f32x4_t;

__device__ inline float bfs2f(unsigned short u){
    unsigned int x = ((unsigned int)u) << 16;
    return __uint_as_float(x);
}
__device__ inline unsigned short f2bfu(float v){
    __hip_bfloat16 h = __float2bfloat16(v);
    return *reinterpret_cast<unsigned short*>(&h);
}
__device__ inline float gelu_tanh(float x){
    float x3 = x*x*x;
    float u = 0.7978845608028654f*(x + 0.044715f*x3);
    float eu = __expf(2.f*u);
    float th = 1.f - 2.f/(eu + 1.f);
    return 0.5f*x*(1.0f + th);
}

// ---------------- workspace layout (float units) ----------------
static const size_t OFF_K     = 0;                                // bf16 [B*S][512]
static const size_t OFF_V     = OFF_K     + (size_t)BB*SS*DA/2;
static const size_t OFF_WCT   = OFF_V     + (size_t)BB*SS*DA/2;   // bf16 [4096][2560]
static const size_t OFF_WC1   = OFF_WCT   + (size_t)NOUT2*KTOT/2; // f32 [512][512]
static const size_t OFF_WOUTT = OFF_WC1   + (size_t)DA*DA;        // bf16 [1024][512]
static const size_t OFF_NW1B  = OFF_WOUTT + (size_t)NPAD*NS/2;    // bf16 [2048][800]
static const size_t OFF_WFK   = OFF_NW1B  + (size_t)DM*MM*HN/2;
static const size_t OFF_WFV   = OFF_WFK   + (size_t)DA*DA;
static const size_t OFF_BFK   = OFF_WFV   + (size_t)DA*DA;
static const size_t OFF_BFV   = OFF_BFK   + DA;
static const size_t OFF_BC1   = OFF_BFV   + DA;
static const size_t OFF_BC2   = OFF_BC1   + DA;
static const size_t OFF_BOUTP = OFF_BC2   + 2*DM;
static const size_t OFF_AA    = OFF_BOUTP + NPAD;                 // f32 2x[64][512]
static const size_t OFF_BA    = OFF_AA    + 2*SB2;
static const size_t OFF_AO    = OFF_BA    + 2*SB2;
static const size_t OFF_BO    = OFF_AO    + 2*SB2;
static const size_t OFF_ATT   = OFF_BO    + 2*SB2;                // bf16 [64][512]
static const size_t OFF_ACTB  = OFF_ATT   + (size_t)BB*DA/2;      // bf16 [b][d]
static const size_t OFF_ACTF  = OFF_ACTB  + (size_t)BB*DM/2;      // f32 [d][b]
static const size_t OFF_HP    = OFF_ACTF  + (size_t)DM*BB;        // f32 [4][64][4096]
static const size_t OFF_SBUF  = OFF_HP    + (size_t)4*BB*2*DM;    // f32 [b][2048]
static const size_t OFF_STATS = OFF_SBUF  + (size_t)BB*DM;        // f32 [64][2]
static const size_t OFF_TRB   = OFF_STATS + 128;                  // bf16 [25][2048][64]
static const size_t OFF_PREDA = OFF_TRB   + (size_t)MM*DM*BB/2;   // bf16 [50][64][1024]
static const size_t OFF_END   = OFF_PREDA + (size_t)TT*BB*NPAD/2;

// ---------------- setup kernels ----------------
__global__ void sgemm64(const float* __restrict__ A, int lda,
                        const float* __restrict__ Bm, int ldb,
                        const float* __restrict__ bias,
                        float* __restrict__ C, int ldc, int Kdim)
{
    __shared__ float la[16][65];
    __shared__ float lb[16][64];
    int cg = blockIdx.x, rg = blockIdx.y, tid = threadIdx.x;
    int tx = tid & 15, ty = tid >> 4;
    const float* Ab = A + (size_t)rg*64*lda;
    const float* Bb = Bm + (size_t)cg*64;
    float acc[4][4] = {};
    for (int k0 = 0; k0 < Kdim; k0 += 16){
        for (int i = tid; i < 1024; i += 256){
            int r = i >> 4, kk = i & 15;
            la[kk][r] = Ab[(size_t)r*lda + k0 + kk];
        }
        for (int i = tid; i < 1024; i += 256){
            int kk = i >> 6, c = i & 63;
            lb[kk][c] = Bb[(size_t)(k0+kk)*ldb + c];
        }
        __syncthreads();
        #pragma unroll
        for (int kk = 0; kk < 16; ++kk){
            float av[4], bv[4];
            #pragma unroll
            for (int i = 0; i < 4; ++i) av[i] = la[kk][ty*4+i];
            #pragma unroll
            for (int j = 0; j < 4; ++j) bv[j] = lb[kk][tx*4+j];
            #pragma unroll
            for (int i = 0; i < 4; ++i)
                #pragma unroll
                for (int j = 0; j < 4; ++j) acc[i][j] += av[i]*bv[j];
        }
        __syncthreads();
    }
    for (int i = 0; i < 4; ++i){
        int row = rg*64 + ty*4 + i;
        for (int j = 0; j < 4; ++j){
            int col = cg*64 + tx*4 + j;
            float v = acc[i][j];
            if (bias) v += bias[col];
            C[(size_t)row*ldc + col] = v;
        }
    }
}

__global__ void sgemm64_bf16out(const float* __restrict__ A, int lda,
                                const float* __restrict__ Bm, int ldb,
                                const float* __restrict__ bias,
                                unsigned short* __restrict__ C, int ldc, int Kdim)
{
    __shared__ float la[16][65];
    __shared__ float lb[16][64];
    int cg = blockIdx.x, rg = blockIdx.y, tid = threadIdx.x;
    int tx = tid & 15, ty = tid >> 4;
    const float* Ab = A + (size_t)rg*64*lda;
    const float* Bb = Bm + (size_t)cg*64;
    float acc[4][4] = {};
    for (int k0 = 0; k0 < Kdim; k0 += 16){
        for (int i = tid; i < 1024; i += 256){
            int r = i >> 4, kk = i & 15;
            la[kk][r] = Ab[(size_t)r*lda + k0 + kk];
        }
        for (int i = tid; i < 1024; i += 256){
            int kk = i >> 6, c = i & 63;
            lb[kk][c] = Bb[(size_t)(k0+kk)*ldb + c];
        }
        __syncthreads();
        #pragma unroll
        for (int kk = 0; kk < 16; ++kk){
            float av[4], bv[4];
            #pragma unroll
            for (int i = 0; i < 4; ++i) av[i] = la[kk][ty*4+i];
            #pragma unroll
            for (int j = 0; j < 4; ++j) bv[j] = lb[kk][tx*4+j];
            #pragma unroll
            for (int i = 0; i < 4; ++i)
                #pragma unroll
                for (int j = 0; j < 4; ++j) acc[i][j] += av[i]*bv[j];
        }
        __syncthreads();
    }
    for (int i = 0; i < 4; ++i){
        int row = rg*64 + ty*4 + i;
        for (int j = 0; j < 4; ++j){
            int col = cg*64 + tx*4 + j;
            float v = acc[i][j];
            if (bias) v += bias[col];
            C[(size_t)row*ldc + col] = f2bfu(v);
        }
    }
}

// Ct[n][k] = bf16((A@B)[k][n]); A 512x512, B 512xN (ldb)
__global__ void gemm_t_bf16(const float* __restrict__ A, const float* __restrict__ Bm,
                            int ldb, unsigned short* __restrict__ Ct, int ldct)
{
    __shared__ float la[16][65];
    __shared__ float lb[16][64];
    int cg = blockIdx.x, rg = blockIdx.y, tid = threadIdx.x;
    int tx = tid & 15, ty = tid >> 4;
    const float* Ab = A + (size_t)rg*64*512;
    const float* Bb = Bm + (size_t)cg*64;
    float acc[4][4] = {};
    for (int k0 = 0; k0 < 512; k0 += 16){
        for (int i = tid; i < 1024; i += 256){
            int r = i >> 4, kk = i & 15;
            la[kk][r] = Ab[(size_t)r*512 + k0 + kk];
        }
        for (int i = tid; i < 1024; i += 256){
            int kk = i >> 6, c = i & 63;
            lb[kk][c] = Bb[(size_t)(k0+kk)*ldb + c];
        }
        __syncthreads();
        #pragma unroll
        for (int kk = 0; kk < 16; ++kk){
            float av[4], bv[4];
            #pragma unroll
            for (int i = 0; i < 4; ++i) av[i] = la[kk][ty*4+i];
            #pragma unroll
            for (int j = 0; j < 4; ++j) bv[j] = lb[kk][tx*4+j];
            #pragma unroll
            for (int i = 0; i < 4; ++i)
                #pragma unroll
                for (int j = 0; j < 4; ++j) acc[i][j] += av[i]*bv[j];
        }
        __syncthreads();
    }
    for (int i = 0; i < 4; ++i){
        int krow = rg*64 + ty*4 + i;
        for (int j = 0; j < 4; ++j){
            int ncol = cg*64 + tx*4 + j;
            Ct[(size_t)ncol*ldct + krow] = f2bfu(acc[i][j]);
        }
    }
}

__global__ void tcvt_ws1(const float* __restrict__ Ws1, unsigned short* __restrict__ WcT)
{
    __shared__ float tile[32][33];
    int bx = blockIdx.x, by = blockIdx.y;
    int tx = threadIdx.x & 31, ty = threadIdx.x >> 5;
    for (int i = 0; i < 4; ++i){
        int r = by*32 + ty + i*8;
        tile[ty + i*8][tx] = Ws1[(size_t)(512 + r)*NOUT2 + bx*32 + tx];
    }
    __syncthreads();
    for (int i = 0; i < 4; ++i){
        int n = bx*32 + ty + i*8;
        int r = by*32 + tx;
        WcT[(size_t)n*KTOT + 512 + r] = f2bfu(tile[tx][ty + i*8]);
    }
}

__global__ void tcvt_wout(const float* __restrict__ Wout, const float* __restrict__ bout,
                          unsigned short* __restrict__ WoutT, float* __restrict__ boutp)
{
    int n = blockIdx.x;
    int tid = threadIdx.x;
    for (int k = tid; k < NS; k += 256)
        WoutT[(size_t)n*NS + k] = (n < NOUT) ? f2bfu(Wout[(size_t)k*NOUT + n]) : (unsigned short)0;
    if (tid == 0) boutp[n] = (n < NOUT) ? bout[n] : 0.f;
}

__global__ void bias_combo(const float* __restrict__ bvec, const float* __restrict__ W,
                           int ldw, const float* __restrict__ badd,
                           float* __restrict__ out, int N)
{
    int n = blockIdx.x*256 + threadIdx.x;
    if (n >= N) return;
    float acc = badd[n];
    for (int k = 0; k < 512; ++k) acc += bvec[k]*W[(size_t)k*ldw + n];
    out[n] = acc;
}

__global__ void cvt_bf16(const float* __restrict__ in, unsigned short* __restrict__ out, int n)
{
    int i = blockIdx.x*256 + threadIdx.x;
    if (i < n) out[i] = f2bfu(in[i]);
}

__global__ void init_state(const float* __restrict__ ss,
                           const int* __restrict__ ilo, const int* __restrict__ iro,
                           float* __restrict__ act_f, unsigned short* __restrict__ act_bf,
                           float* __restrict__ aA0, float* __restrict__ bA0,
                           float* __restrict__ aO0, float* __restrict__ bO0)
{
    int i = blockIdx.x*256 + threadIdx.x;
    if (i < BB*DM){
        int d = i >> 6, b = i & 63;
        float v = ss[d];
        act_f[(size_t)d*BB + b] = v;
        act_bf[(size_t)b*DM + d] = f2bfu(v);
    }
    if (i < BB*NS){
        int j = i & (NS-1);
        aA0[i] = 0.f; bA0[i] = 0.f;
        aO0[i] = ss[ilo[j]]*ss[iro[j]];
        bO0[i] = 1.f;
    }
}

// ---------------- per-tick kernels ----------------
// pred for tick tp: syO computed redundantly in-LDS per block; block 0 persists state.
__device__ void pred_body(char* smem, int pb,
                          const float* __restrict__ act_f,
                          float* __restrict__ aO, float* __restrict__ bO,
                          const int* __restrict__ ilo, const int* __restrict__ iro,
                          const float* __restrict__ dco,
                          const unsigned short* __restrict__ WoutT,
                          const float* __restrict__ boutp,
                          unsigned short* __restrict__ predA,
                          float* __restrict__ out_syo, int tp)
{
    unsigned short* Asy = (unsigned short*)smem;   // [64][72]
    const int tid = threadIdx.x, lane = tid & 63, w = tid >> 6;
    const int rf = w & 3, cf2 = (w >> 2)*2;
    const int colb = lane & 15, koff = (lane >> 4)*8, rg4 = (lane >> 4)*4;
    const int n0 = pb*64;
    const int rdn = tp & 1, wrn = 1 - rdn;
    f32x4_t acc0 = {0.f,0.f,0.f,0.f}, acc1 = {0.f,0.f,0.f,0.f};
    for (int ks = 0; ks < 8; ++ks){
        int jj = tid & 63, bq = tid >> 6;
        int j = ks*64 + jj;
        int ilj = ilo[j], irj = iro[j];
        float rr = __expf(-fminf(fmaxf(dco[j], 0.f), 15.f));
        #pragma unroll
        for (int p = 0; p < 8; ++p){
            int b = p*8 + bq;
            float pair = act_f[(size_t)ilj*BB + b]*act_f[(size_t)irj*BB + b];
            size_t o = (size_t)b*NS + j;
            float a  = rr*aO[(size_t)rdn*SB2 + o] + pair;
            float be = rr*bO[(size_t)rdn*SB2 + o] + 1.f;
            float s = a*rsqrtf(be);
            Asy[b*72 + jj] = f2bfu(s);
            if (pb == 0){
                aO[(size_t)wrn*SB2 + o] = a;
                bO[(size_t)wrn*SB2 + o] = be;
                if (tp == TT-1) out_syo[o] = s;
            }
        }
        __syncthreads();
        int arow = rf*16 + colb;
        bf16x8_t a0 = *(const bf16x8_t*)&Asy[arow*72 + koff];
        bf16x8_t a1 = *(const bf16x8_t*)&Asy[arow*72 + 32 + koff];
        int br0 = n0 + cf2*16 + colb, br1 = br0 + 16;
        bf16x8_t b00 = *(const bf16x8_t*)&WoutT[(size_t)br0*NS + ks*64 + koff];
        bf16x8_t b01 = *(const bf16x8_t*)&WoutT[(size_t)br0*NS + ks*64 + 32 + koff];
        bf16x8_t b10 = *(const bf16x8_t*)&WoutT[(size_t)br1*NS + ks*64 + koff];
        bf16x8_t b11 = *(const bf16x8_t*)&WoutT[(size_t)br1*NS + ks*64 + 32 + koff];
        acc0 = __builtin_amdgcn_mfma_f32_16x16x32_bf16(a0, b00, acc0, 0, 0, 0);
        acc0 = __builtin_amdgcn_mfma_f32_16x16x32_bf16(a1, b01, acc0, 0, 0, 0);
        acc1 = __builtin_amdgcn_mfma_f32_16x16x32_bf16(a0, b10, acc1, 0, 0, 0);
        acc1 = __builtin_amdgcn_mfma_f32_16x16x32_bf16(a1, b11, acc1, 0, 0, 0);
        __syncthreads();
    }
    unsigned short* pa = predA + (size_t)tp*BB*NPAD;
    #pragma unroll
    for (int r = 0; r < 4; ++r){
        int row = rf*16 + rg4 + r;
        int c0 = n0 + cf2*16 + colb, c1 = c0 + 16;
        pa[(size_t)row*NPAD + c0] = f2bfu(acc0[r] + boutp[c0]);
        pa[(size_t)row*NPAD + c1] = f2bfu(acc1[r] + boutp[c1]);
    }
}

// blocks 0..63: syncA(t)+Qh+attention (head bid>>3, batches (bid&7)*8..+7)
// blocks 64..79: pred(t-1) when do_pred
__global__ __launch_bounds__(512) void tick_head(
        const float* __restrict__ act_f,
        float* __restrict__ aA, float* __restrict__ bA,
        float* __restrict__ aO, float* __restrict__ bO,
        const int* __restrict__ ila, const int* __restrict__ ira,
        const int* __restrict__ ilo, const int* __restrict__ iro,
        const float* __restrict__ dca, const float* __restrict__ dco,
        const float* __restrict__ Wc1, const float* __restrict__ bc1,
        const unsigned short* __restrict__ Kb, const unsigned short* __restrict__ Vb,
        unsigned short* __restrict__ att,
        const unsigned short* __restrict__ WoutT, const float* __restrict__ boutp,
        unsigned short* __restrict__ predA, float* __restrict__ out_syo,
        int t, int do_pred)
{
    __shared__ __align__(16) char smem[20480];
    const int bid = blockIdx.x, tid = threadIdx.x;
    const int lane = tid & 63, w = tid >> 6;
    if (bid < 64){
        int h = bid >> 3, bg = bid & 7;
        float* sy  = (float*)smem;          // [8][512]
        float* q   = sy + 8*NS;             // [8][64]
        float* wgt = q + 8*64;              // [8][64]
        int rdn = t & 1, wrn = 1 - rdn;
        for (int i = tid; i < 8*NS; i += 512){
            int r = i >> 9, j = i & (NS-1);
            int b = bg*8 + r;
            float pair = act_f[(size_t)ila[j]*BB + b]*act_f[(size_t)ira[j]*BB + b];
            float rr = __expf(-fminf(fmaxf(dca[j], 0.f), 15.f));
            size_t o = (size_t)b*NS + j;
            float a  = rr*aA[(size_t)rdn*SB2 + o] + pair;
            float be = rr*bA[(size_t)rdn*SB2 + o] + 1.f;
            sy[i] = a*rsqrtf(be);
            if (h == 0){ aA[(size_t)wrn*SB2 + o] = a; bA[(size_t)wrn*SB2 + o] = be; }
        }
        __syncthreads();
        {   // Qh: r = w (batch), c = lane
            int c = lane, r = w;
            int col = h*HD + c;
            float acc = bc1[col];
            const float* wp = Wc1 + col;
            #pragma unroll 8
            for (int k = 0; k < NS; ++k) acc += sy[r*NS + k]*wp[(size_t)k*DA];
            q[r*64 + c] = acc;
        }
        __syncthreads();
        {   // scores + softmax: wave r handles batch bg*8+r, lane = s
            int r = w, s = lane;
            int b = bg*8 + r;
            const unsigned short* kp = Kb + (size_t)(b*SS + s)*DA + h*HD;
            float sc = 0.f;
            #pragma unroll
            for (int dg = 0; dg < 8; ++dg){
                u16x8_t kv = *(const u16x8_t*)(kp + dg*8);
                #pragma unroll
                for (int u = 0; u < 8; ++u) sc += q[r*64 + dg*8 + u]*bfs2f(kv[u]);
            }
            sc *= 0.125f;
            float m = sc;
            for (int o = 32; o; o >>= 1) m = fmaxf(m, __shfl_xor(m, o, 64));
            float e = __expf(sc - m);
            float sum = e;
            for (int o = 32; o; o >>= 1) sum += __shfl_xor(sum, o, 64);
            wgt[r*64 + s] = e/sum;
        }
        __syncthreads();
        {   // PV: wave r, lane = d
            int r = w, d = lane;
            int b = bg*8 + r;
            const unsigned short* vp = Vb + (size_t)(b*SS)*DA + h*HD + d;
            float o = 0.f;
            #pragma unroll 8
            for (int s = 0; s < SS; ++s) o += wgt[r*64 + s]*bfs2f(vp[(size_t)s*DA]);
            att[(size_t)b*DA + h*HD + d] = f2bfu(o);
        }
    } else if (do_pred){
        pred_body(smem, bid - 64, act_f, aO, bO, ilo, iro, dco,
                  WoutT, boutp, predA, out_syo, t - 1);
    }
}

__global__ __launch_bounds__(512) void pred_fin(
        const float* __restrict__ act_f,
        float* __restrict__ aO, float* __restrict__ bO,
        const int* __restrict__ ilo, const int* __restrict__ iro,
        const float* __restrict__ dco,
        const unsigned short* __restrict__ WoutT, const float* __restrict__ boutp,
        unsigned short* __restrict__ predA, float* __restrict__ out_syo)
{
    __shared__ __align__(16) char smem[10240];
    pred_body(smem, blockIdx.x, act_f, aO, bO, ilo, iro, dco,
              WoutT, boutp, predA, out_syo, TT - 1);
}

// bf16 MFMA GEMM: h = [att | act] @ WcT^T, split-K x4, BK=64.  grid(64,4), 256 thr.
__global__ __launch_bounds__(256) void hgemm_mfma(const unsigned short* __restrict__ attu,
                                                  const unsigned short* __restrict__ actu,
                                                  const unsigned short* __restrict__ wctu,
                                                  float* __restrict__ hpart)
{
    __shared__ unsigned short Al[64][72];
    __shared__ unsigned short Bl[64][72];
    int cg = blockIdx.x, kc = blockIdx.y, tid = threadIdx.x;
    int w = tid >> 6, lane = tid & 63;
    int n0 = cg*64;
    f32x4_t acc[4];
    #pragma unroll
    for (int t2 = 0; t2 < 4; ++t2) acc[t2] = (f32x4_t){0.f,0.f,0.f,0.f};

    for (int step = 0; step < 10; ++step){
        int k0 = kc*KCH + step*64;
        #pragma unroll
        for (int ld = 0; ld < 2; ++ld){
            int idx = tid + ld*256;
            int row = idx >> 3;
            int kg  = (idx & 7)*8;
            *reinterpret_cast<uint4*>(&Bl[row][kg]) =
                *reinterpret_cast<const uint4*>(&wctu[(size_t)(n0+row)*KTOT + k0 + kg]);
            uint4 av;
            if (k0 < 512) av = *reinterpret_cast<const uint4*>(&attu[(size_t)row*DA + k0 + kg]);
            else          av = *reinterpret_cast<const uint4*>(&actu[(size_t)row*DM + (k0-512) + kg]);
            *reinterpret_cast<uint4*>(&Al[row][kg]) = av;
        }
        __syncthreads();
        int arow = w*16 + (lane & 15);
        int koff = (lane >> 4)*8;
        bf16x8_t af0 = *reinterpret_cast<const bf16x8_t*>(&Al[arow][koff]);
        bf16x8_t af1 = *reinterpret_cast<const bf16x8_t*>(&Al[arow][32 + koff]);
        #pragma unroll
        for (int t2 = 0; t2 < 4; ++t2){
            int brow = t2*16 + (lane & 15);
            bf16x8_t bf0 = *reinterpret_cast<const bf16x8_t*>(&Bl[brow][koff]);
            bf16x8_t bf1 = *reinterpret_cast<const bf16x8_t*>(&Bl[brow][32 + koff]);
            acc[t2] = __builtin_amdgcn_mfma_f32_16x16x32_bf16(af0, bf0, acc[t2], 0, 0, 0);
            acc[t2] = __builtin_amdgcn_mfma_f32_16x16x32_bf16(af1, bf1, acc[t2], 0, 0, 0);
        }
        __syncthreads();
    }
    float* out = hpart + (size_t)kc*BB*2*DM;
    int colb = lane & 15, rg2 = (lane >> 4)*4;
    #pragma unroll
    for (int t2 = 0; t2 < 4; ++t2){
        #pragma unroll
        for (int r = 0; r < 4; ++r){
            int row = w*16 + rg2 + r;
            int col = n0 + t2*16 + colb;
            out[(size_t)row*2*DM + col] = acc[t2][r];
        }
    }
}

// GLU over 4 split-K partials + LN stats; writes sbuf[b][d] f32 + stats[b]
__global__ void glu_stats(const float* __restrict__ hp, const float* __restrict__ bc2,
                          float* __restrict__ sbuf, float* __restrict__ stats)
{
    __shared__ float red[8];
    int b = blockIdx.x, tid = threadIdx.x;
    int lane = tid & 63, w = tid >> 6;
    float lsum = 0.f, lsq = 0.f;
    #pragma unroll
    for (int i = 0; i < 8; ++i){
        int n = tid + i*256;
        float h1 = bc2[n], h2 = bc2[DM + n];
        #pragma unroll
        for (int c = 0; c < 4; ++c){
            const float* hb = hp + ((size_t)c*BB + b)*2*DM;
            h1 += hb[n]; h2 += hb[DM + n];
        }
        float s = h1*(1.f/(1.f + __expf(-h2)));
        sbuf[(size_t)b*DM + n] = s;
        lsum += s; lsq += s*s;
    }
    for (int o = 32; o; o >>= 1){ lsum += __shfl_down(lsum, o, 64); lsq += __shfl_down(lsq, o, 64); }
    if (lane == 0){ red[w] = lsum; red[4 + w] = lsq; }
    __syncthreads();
    if (tid == 0){
        float ts = red[0]+red[1]+red[2]+red[3];
        float tq = red[4]+red[5]+red[6]+red[7];
        float mu = ts/DM;
        float var = tq/DM - mu*mu;
        stats[b*2] = mu;
        stats[b*2+1] = rsqrtf(var + 1e-5f);
    }
}

// nlm: wave w handles d = bid*8+w; lane = batch.  Applies LN, writes trace+act.
__global__ __launch_bounds__(512) void nlm2(
        const float* __restrict__ sbuf, const float* __restrict__ stats,
        const float* __restrict__ lng, const float* __restrict__ lnb,
        unsigned short* __restrict__ traceb, const float* __restrict__ stt,
        const unsigned short* __restrict__ nw1b, const float* __restrict__ nb1,
        const float* __restrict__ nw2, const float* __restrict__ nb2,
        float* __restrict__ act_f, unsigned short* __restrict__ act_bf, int t)
{
    __shared__ float wall[8*864];
    const int tid = threadIdx.x, lane = tid & 63, w = tid >> 6;
    const int d = blockIdx.x*8 + w;
    float* wreg = wall + (size_t)w*864;     // [800 w1][32 nb1][32 nw2]
    for (int i = lane; i < 800; i += 64) wreg[i] = bfs2f(nw1b[(size_t)d*800 + i]);
    if (lane < 32) wreg[800 + lane] = nb1[d*HN + lane];
    else           wreg[832 + (lane - 32)] = nw2[d*HN + (lane - 32)];
    float mu  = stats[lane*2];
    float inv = stats[lane*2 + 1];
    float s   = sbuf[(size_t)lane*DM + d];
    float st  = (s - mu)*inv*lng[d] + lnb[d];
    int slot = t % MM;
    traceb[((size_t)slot*DM + d)*BB + lane] = f2bfu(st);
    float tr[25];
    #pragma unroll
    for (int m = 0; m < 24; ++m){
        int time = t - 24 + m;
        tr[m] = (time >= 0) ? bfs2f(traceb[((size_t)(time % MM)*DM + d)*BB + lane])
                            : stt[(size_t)d*MM + (m + t + 1)];
    }
    tr[24] = st;
    float a[32];
    #pragma unroll
    for (int h = 0; h < 32; ++h) a[h] = wreg[800 + h];
    #pragma unroll
    for (int m = 0; m < 25; ++m){
        float tm = tr[m];
        #pragma unroll
        for (int q4 = 0; q4 < 8; ++q4){
            float4 w4 = *(const float4*)&wreg[m*32 + q4*4];
            a[q4*4+0] += tm*w4.x;
            a[q4*4+1] += tm*w4.y;
            a[q4*4+2] += tm*w4.z;
            a[q4*4+3] += tm*w4.w;
        }
    }
    float pa = 0.f;
    #pragma unroll
    for (int h = 0; h < 32; ++h) pa += gelu_tanh(a[h])*wreg[832 + h];
    float v = pa + nb2[d];
    act_f[(size_t)d*BB + lane] = v;
    act_bf[(size_t)lane*DM + d] = f2bfu(v);
}

// ---------------- post-loop kernels ----------------
__global__ void entropy_k(const unsigned short* __restrict__ predA, float* __restrict__ out_cert)
{
    __shared__ float red[8];
    int b = blockIdx.x & 63, t = blockIdx.x >> 6, tid = threadIdx.x;
    const unsigned short* pr = predA + (size_t)t*BB*NPAD + (size_t)b*NPAD;
    float v[4];
    float m = -1e30f;
    #pragma unroll
    for (int i = 0; i < 4; ++i){
        int n = tid + i*256;
        v[i] = (n < NOUT) ? bfs2f(pr[n]) : -1e30f;
        m = fmaxf(m, v[i]);
    }
    for (int o = 32; o; o >>= 1) m = fmaxf(m, __shfl_xor(m, o, 64));
    if ((tid & 63) == 0) red[tid >> 6] = m;
    __syncthreads();
    m = fmaxf(fmaxf(red[0], red[1]), fmaxf(red[2], red[3]));
    __syncthreads();
    float s1 = 0.f, s2 = 0.f;
    #pragma unroll
    for (int i = 0; i < 4; ++i){
        int n = tid + i*256;
        if (n < NOUT){
            float e = __expf(v[i] - m);
            s1 += e; s2 += e*(v[i] - m);
        }
    }
    for (int o = 32; o; o >>= 1){ s1 += __shfl_xor(s1, o, 64); s2 += __shfl_xor(s2, o, 64); }
    if ((tid & 63) == 0){ red[tid >> 6] = s1; red[4 + (tid >> 6)] = s2; }
    __syncthreads();
    s1 = red[0]+red[1]+red[2]+red[3];
    s2 = red[4]+red[5]+red[6]+red[7];
    float plogp = s2/s1 - logf(s1);
    float ne = -plogp / logf((float)NOUT);
    if (tid == 0){
        out_cert[(size_t)b*2*TT + t]      = ne;
        out_cert[(size_t)b*2*TT + TT + t] = 1.f - ne;
    }
}

__global__ void transpose_pred(const unsigned short* __restrict__ predA, float* __restrict__ out_pred)
{
    __shared__ unsigned short sm[50][136];
    int bx = blockIdx.x;
    int b  = blockIdx.y;
    int tid = threadIdx.x;
    for (int tp = 0; tp < 25; ++tp){
        int t = tp*2 + (tid >> 7);
        int nn = tid & 127;
        sm[t][nn] = predA[(size_t)t*BB*NPAD + (size_t)b*NPAD + bx*128 + nn];
    }
    __syncthreads();
    int nloc = tid >> 1, half = tid & 1;
    int n = bx*128 + nloc;
    if (n < NOUT){
        float* dst = out_pred + (size_t)b*NOUT*TT + (size_t)n*TT + half*25;
        #pragma unroll
        for (int q = 0; q < 25; ++q) dst[q] = bfs2f(sm[half*25 + q][nloc]);
    }
}

extern "C" void kernel_launch(void* const* d_in, const int* in_sizes, int n_in,
                              void* d_out, int out_size, void* d_ws, size_t ws_size,
                              hipStream_t stream)
{
    const float* x    = (const float*)d_in[0];
    const float* Wf   = (const float*)d_in[1];
    const float* bf   = (const float*)d_in[2];
    const float* stt  = (const float*)d_in[3];
    const float* ss   = (const float*)d_in[4];
    const float* dca  = (const float*)d_in[5];
    const float* dco  = (const float*)d_in[6];
    const float* Wqp  = (const float*)d_in[7];
    const float* bqp  = (const float*)d_in[8];
    const float* Wq   = (const float*)d_in[9];
    const float* bq   = (const float*)d_in[10];
    const float* Wk   = (const float*)d_in[11];
    const float* bk   = (const float*)d_in[12];
    const float* Wv   = (const float*)d_in[13];
    const float* bv   = (const float*)d_in[14];
    const float* Wo   = (const float*)d_in[15];
    const float* bo   = (const float*)d_in[16];
    const float* Ws1  = (const float*)d_in[17];
    const float* bs1  = (const float*)d_in[18];
    const float* lng  = (const float*)d_in[19];
    const float* lnb  = (const float*)d_in[20];
    const float* nw1  = (const float*)d_in[21];
    const float* nb1  = (const float*)d_in[22];
    const float* nw2  = (const float*)d_in[23];
    const float* nb2  = (const float*)d_in[24];
    const float* Wout = (const float*)d_in[25];
    const float* bout = (const float*)d_in[26];
    const int* ila = (const int*)d_in[27];
    const int* ira = (const int*)d_in[28];
    const int* ilo = (const int*)d_in[29];
    const int* iro = (const int*)d_in[30];

    float* ws = (float*)d_ws;
    unsigned short* Kb    = (unsigned short*)(ws + OFF_K);
    unsigned short* Vb    = (unsigned short*)(ws + OFF_V);
    unsigned short* WcT   = (unsigned short*)(ws + OFF_WCT);
    float*          Wc1   = ws + OFF_WC1;
    unsigned short* WoutT = (unsigned short*)(ws + OFF_WOUTT);
    unsigned short* nw1b  = (unsigned short*)(ws + OFF_NW1B);
    float* Wfk   = ws + OFF_WFK;
    float* Wfv   = ws + OFF_WFV;
    float* bfk   = ws + OFF_BFK;
    float* bfv   = ws + OFF_BFV;
    float* bc1   = ws + OFF_BC1;
    float* bc2   = ws + OFF_BC2;
    float* boutp = ws + OFF_BOUTP;
    float* aA    = ws + OFF_AA;
    float* bA    = ws + OFF_BA;
    float* aO    = ws + OFF_AO;
    float* bO    = ws + OFF_BO;
    unsigned short* attb  = (unsigned short*)(ws + OFF_ATT);
    unsigned short* actb  = (unsigned short*)(ws + OFF_ACTB);
    float* actf  = ws + OFF_ACTF;
    float* hp    = ws + OFF_HP;
    float* sbuf  = ws + OFF_SBUF;
    float* stats = ws + OFF_STATS;
    unsigned short* traceb = (unsigned short*)(ws + OFF_TRB);
    unsigned short* predA  = (unsigned short*)(ws + OFF_PREDA);

    float* outp = (float*)d_out;
    float* out_pred = outp;
    float* out_cert = outp + (size_t)BB*NOUT*TT;
    float* out_syo  = out_cert + (size_t)BB*2*TT;

    // ---- setup ----
    sgemm64<<<dim3(8,8),  256, 0, stream>>>(Wf, 512, Wk, 512, nullptr, Wfk, 512, 512);
    sgemm64<<<dim3(8,8),  256, 0, stream>>>(Wf, 512, Wv, 512, nullptr, Wfv, 512, 512);
    sgemm64<<<dim3(8,8),  256, 0, stream>>>(Wqp,512, Wq, 512, nullptr, Wc1, 512, 512);
    gemm_t_bf16<<<dim3(64,8), 256, 0, stream>>>(Wo, Ws1, NOUT2, WcT, KTOT);
    tcvt_ws1<<<dim3(128,64), 256, 0, stream>>>(Ws1, WcT);
    tcvt_wout<<<NPAD, 256, 0, stream>>>(Wout, bout, WoutT, boutp);
    bias_combo<<<2, 256, 0, stream>>>(bf,  Wk, 512, bk, bfk, 512);
    bias_combo<<<2, 256, 0, stream>>>(bf,  Wv, 512, bv, bfv, 512);
    bias_combo<<<2, 256, 0, stream>>>(bqp, Wq, 512, bq, bc1, 512);
    bias_combo<<<16,256, 0, stream>>>(bo,  Ws1, NOUT2, bs1, bc2, 4096);
    cvt_bf16<<<6400, 256, 0, stream>>>(nw1, nw1b, DM*MM*HN);
    sgemm64_bf16out<<<dim3(8,64), 256, 0, stream>>>(x, 512, Wfk, 512, bfk, Kb, 512, 512);
    sgemm64_bf16out<<<dim3(8,64), 256, 0, stream>>>(x, 512, Wfv, 512, bfv, Vb, 512, 512);
    init_state<<<512, 256, 0, stream>>>(ss, ilo, iro, actf, actb, aA, bA, aO, bO);

    // ---- tick loop: 4 launches per tick ----
    for (int t = 0; t < TT; ++t){
        tick_head<<<80, 512, 0, stream>>>(actf, aA, bA, aO, bO,
                                          ila, ira, ilo, iro, dca, dco,
                                          Wc1, bc1, Kb, Vb, attb,
                                          WoutT, boutp, predA, out_syo,
                                          t, (t > 0) ? 1 : 0);
        hgemm_mfma<<<dim3(64,4), 256, 0, stream>>>(attb, actb, WcT, hp);
        glu_stats<<<BB, 256, 0, stream>>>(hp, bc2, sbuf, stats);
        nlm2<<<256, 512, 0, stream>>>(sbuf, stats, lng, lnb, traceb, stt,
                                      nw1b, nb1, nw2, nb2, actf, actb, t);
    }
    pred_fin<<<16, 512, 0, stream>>>(actf, aO, bO, ilo, iro, dco,
                                     WoutT, boutp, predA, out_syo);

    // ---- outputs ----
    entropy_k<<<TT*BB, 256, 0, stream>>>(predA, out_cert);
    transpose_pred<<<dim3(8, BB), 256, 0, stream>>>(predA, out_pred);
}